// Round 1
// baseline (379.684 us; speedup 1.0000x reference)
//
#include <hip/hip_runtime.h>
#include <hip/hip_bf16.h>

// Mamba 2D layer, fp32. B=4, C=128, H=W=64 -> L=4096.
// D_INNER=256, D_STATE=16, D_CONV=4, DT_RANK=8.
#define B_ 4
#define CDIM 128
#define L_ 4096
#define DIN 256
#define DST 16
#define DTR 8
#define NC 64   // scan chunks
#define CS 64   // chunk size (L_/NC)

// ---------------- LayerNorm: x (B,C,L) -> xn (B,L,C) ----------------
__global__ __launch_bounds__(256) void k_ln(const float* __restrict__ x,
                                            const float* __restrict__ nw,
                                            const float* __restrict__ nb,
                                            float* __restrict__ xn) {
  const int b = blockIdx.y;
  const int l0 = blockIdx.x * 64;
  __shared__ float xs[64][129];
  __shared__ float mu[64], rs[64];
  for (int i = threadIdx.x; i < CDIM * 64; i += 256) {
    int c = i >> 6, ll = i & 63;           // coalesced over l
    xs[ll][c] = x[((size_t)(b * CDIM + c)) * L_ + l0 + ll];
  }
  __syncthreads();
  if (threadIdx.x < 64) {
    int ll = threadIdx.x;
    float s = 0.f;
    for (int c = 0; c < CDIM; ++c) s += xs[ll][c];
    float m = s * (1.f / CDIM);
    float v = 0.f;
    for (int c = 0; c < CDIM; ++c) { float t = xs[ll][c] - m; v += t * t; }
    mu[ll] = m;
    rs[ll] = rsqrtf(v * (1.f / CDIM) + 1e-5f);
  }
  __syncthreads();
  for (int i = threadIdx.x; i < CDIM * 64; i += 256) {
    int ll = i >> 7, c = i & 127;          // coalesced over c
    float v = (xs[ll][c] - mu[ll]) * rs[ll] * nw[c] + nb[c];
    xn[((size_t)(b * L_ + l0 + ll)) * CDIM + c] = v;
  }
}

// ------------- in_proj: xn (16384,128) @ W(512,128)^T -> xin, z -------------
__global__ __launch_bounds__(256) void k_inproj(const float* __restrict__ A,
                                                const float* __restrict__ W,
                                                float* __restrict__ xin,
                                                float* __restrict__ z) {
  const int bn = blockIdx.x * 64, bm = blockIdx.y * 64;
  __shared__ float As[32][65];
  __shared__ float Ws[32][65];
  float acc[4][4] = {};
  const int tx = threadIdx.x & 15, ty = threadIdx.x >> 4;
  for (int k0 = 0; k0 < 128; k0 += 32) {
    for (int i = threadIdx.x; i < 64 * 32; i += 256) {
      int m = i >> 5, k = i & 31;
      As[k][m] = A[(size_t)(bm + m) * CDIM + k0 + k];
    }
    for (int i = threadIdx.x; i < 64 * 32; i += 256) {
      int n = i >> 5, k = i & 31;
      Ws[k][n] = W[(size_t)(bn + n) * CDIM + k0 + k];
    }
    __syncthreads();
    for (int k = 0; k < 32; ++k) {
      float a[4], bv[4];
      for (int i = 0; i < 4; ++i) a[i] = As[k][ty * 4 + i];
      for (int j = 0; j < 4; ++j) bv[j] = Ws[k][tx * 4 + j];
      for (int i = 0; i < 4; ++i)
        for (int j = 0; j < 4; ++j) acc[i][j] += a[i] * bv[j];
    }
    __syncthreads();
  }
  for (int i = 0; i < 4; ++i) {
    int m = bm + ty * 4 + i;
    for (int j = 0; j < 4; ++j) {
      int n = bn + tx * 4 + j;
      float v = acc[i][j];
      if (n < DIN) xin[(size_t)m * DIN + n] = v;
      else         z[(size_t)m * DIN + (n - DIN)] = v;
    }
  }
}

// ---------------- causal conv (d_conv=4) + SiLU ----------------
__global__ void k_conv(const float* __restrict__ xin, const float* __restrict__ cw,
                       const float* __restrict__ cb, float* __restrict__ xc) {
  int idx = blockIdx.x * 256 + threadIdx.x;
  if (idx >= B_ * L_ * DIN) return;
  int d = idx & 255;
  int bl = idx >> 8;
  int l = bl & (L_ - 1);
  int b = bl >> 12;
  float acc = cb[d];
  for (int k = 0; k < 4; ++k) {
    int ls = l + k - 3;
    float v = (ls >= 0) ? xin[((size_t)(b * L_ + ls)) * DIN + d] : 0.f;
    acc += v * cw[d * 4 + k];
  }
  xc[idx] = acc / (1.f + __expf(-acc));  // silu
}

// ---------------- x_proj: xc (16384,256) @ W(40,256)^T -> dbl ----------------
__global__ __launch_bounds__(256) void k_xproj(const float* __restrict__ xc,
                                               const float* __restrict__ w,
                                               float* __restrict__ dbl) {
  const int bl0 = blockIdx.x * 16;
  __shared__ float xs[16][260];
  for (int i = threadIdx.x; i < 16 * 256; i += 256) {
    int r = i >> 8, d = i & 255;
    xs[r][d] = xc[(size_t)(bl0 + r) * DIN + d];
  }
  __syncthreads();
  for (int o = threadIdx.x; o < 16 * 40; o += 256) {
    int r = o / 40, e = o % 40;
    const float* wr = w + e * DIN;
    float s = 0.f;
    for (int k = 0; k < DIN; ++k) s += xs[r][k] * wr[k];
    dbl[(size_t)(bl0 + r) * 40 + e] = s;
  }
}

// ---------------- delta = softplus(dt @ dt_proj_w^T + b) ----------------
__global__ void k_delta(const float* __restrict__ dbl, const float* __restrict__ w,
                        const float* __restrict__ bias, float* __restrict__ delta) {
  int idx = blockIdx.x * 256 + threadIdx.x;
  if (idx >= B_ * L_ * DIN) return;
  int d = idx & 255;
  size_t bl = idx >> 8;
  const float* dt = dbl + bl * 40;
  const float* wr = w + d * DTR;
  float s = bias[d];
  for (int r = 0; r < DTR; ++r) s += dt[r] * wr[r];
  delta[idx] = (s > 20.f) ? s : __logf(1.f + __expf(s));
}

// ---------------- scan pass 1: per-chunk (P=prod a, Q=partial h) ----------------
__global__ __launch_bounds__(256) void k_scan1(const float* __restrict__ delta,
                                               const float* __restrict__ xc,
                                               const float* __restrict__ dbl,
                                               const float* __restrict__ A_log,
                                               float* __restrict__ P,
                                               float* __restrict__ Q) {
  const int b = blockIdx.y, c = blockIdx.x, d = threadIdx.x;
  const int l0 = c * CS;
  __shared__ float Bs[CS][DST];
  for (int i = threadIdx.x; i < CS * DST; i += 256) {
    int ll = i >> 4, n = i & 15;
    Bs[ll][n] = dbl[((size_t)(b * L_ + l0 + ll)) * 40 + DTR + n];
  }
  float An[DST];
  for (int n = 0; n < DST; ++n) An[n] = -__expf(A_log[d * DST + n]);
  float p[DST], q[DST];
  for (int n = 0; n < DST; ++n) { p[n] = 1.f; q[n] = 0.f; }
  __syncthreads();
  for (int ll = 0; ll < CS; ++ll) {
    size_t bl = (size_t)(b * L_ + l0 + ll);
    float dv = delta[bl * DIN + d];
    float du = dv * xc[bl * DIN + d];
    for (int n = 0; n < DST; ++n) {
      float a = __expf(dv * An[n]);
      p[n] *= a;
      q[n] = a * q[n] + du * Bs[ll][n];
    }
  }
  size_t base = (((size_t)b * NC + c) * DIN + d) * DST;
  for (int n = 0; n < DST; ++n) { P[base + n] = p[n]; Q[base + n] = q[n]; }
}

// ---------------- scan pass 2: sequential combine over chunks ----------------
__global__ void k_scan2(const float* __restrict__ P, const float* __restrict__ Q,
                        float* __restrict__ Hin) {
  int idx = blockIdx.x * 256 + threadIdx.x;  // B*DIN*DST = 16384
  int b = idx / (DIN * DST);
  int dn = idx % (DIN * DST);
  float h = 0.f;
  size_t base = ((size_t)b * NC) * (DIN * DST) + dn;
  float p = P[base], q = Q[base];
  for (int c = 0; c < NC; ++c) {
    size_t nb = base + (size_t)(c + 1) * (DIN * DST);
    float pn = 0.f, qn = 0.f;
    if (c + 1 < NC) { pn = P[nb]; qn = Q[nb]; }
    Hin[base + (size_t)c * (DIN * DST)] = h;
    h = p * h + q;
    p = pn; q = qn;
  }
}

// ---------------- scan pass 3: replay with entry state, fuse D/z-gate ----------------
__global__ __launch_bounds__(256) void k_scan3(const float* __restrict__ delta,
                                               const float* __restrict__ xc,
                                               const float* __restrict__ dbl,
                                               const float* __restrict__ A_log,
                                               const float* __restrict__ Hin,
                                               const float* __restrict__ Dp,
                                               const float* __restrict__ z,
                                               float* __restrict__ yfin) {
  const int b = blockIdx.y, c = blockIdx.x, d = threadIdx.x;
  const int l0 = c * CS;
  __shared__ float Bs[CS][DST], Cs2[CS][DST];
  for (int i = threadIdx.x; i < CS * DST; i += 256) {
    int ll = i >> 4, n = i & 15;
    size_t base = ((size_t)(b * L_ + l0 + ll)) * 40;
    Bs[ll][n]  = dbl[base + DTR + n];
    Cs2[ll][n] = dbl[base + DTR + DST + n];
  }
  float An[DST];
  for (int n = 0; n < DST; ++n) An[n] = -__expf(A_log[d * DST + n]);
  float h[DST];
  size_t hb = (((size_t)b * NC + c) * DIN + d) * DST;
  for (int n = 0; n < DST; ++n) h[n] = Hin[hb + n];
  const float Dd = Dp[d];
  __syncthreads();
  for (int ll = 0; ll < CS; ++ll) {
    size_t bl = (size_t)(b * L_ + l0 + ll);
    float dv = delta[bl * DIN + d];
    float xcv = xc[bl * DIN + d];
    float du = dv * xcv;
    float y = 0.f;
    for (int n = 0; n < DST; ++n) {
      float a = __expf(dv * An[n]);
      h[n] = a * h[n] + du * Bs[ll][n];
      y += h[n] * Cs2[ll][n];
    }
    float zv = z[bl * DIN + d];
    float sz = zv / (1.f + __expf(-zv));
    yfin[bl * DIN + d] = (y + xcv * Dd) * sz;
  }
}

// ------------- out_proj: y (16384,256) @ W(128,256)^T -> out (B,C,L) -------------
__global__ __launch_bounds__(256) void k_outproj(const float* __restrict__ Y,
                                                 const float* __restrict__ W,
                                                 float* __restrict__ out) {
  const int bn = blockIdx.x * 64, bm = blockIdx.y * 64;
  __shared__ float As[32][65];
  __shared__ float Ws[32][65];
  __shared__ float ot[64][65];
  float acc[4][4] = {};
  const int tx = threadIdx.x & 15, ty = threadIdx.x >> 4;
  for (int k0 = 0; k0 < DIN; k0 += 32) {
    for (int i = threadIdx.x; i < 64 * 32; i += 256) {
      int m = i >> 5, k = i & 31;
      As[k][m] = Y[(size_t)(bm + m) * DIN + k0 + k];
    }
    for (int i = threadIdx.x; i < 64 * 32; i += 256) {
      int n = i >> 5, k = i & 31;
      Ws[k][n] = W[(size_t)(bn + n) * DIN + k0 + k];
    }
    __syncthreads();
    for (int k = 0; k < 32; ++k) {
      float a[4], bv[4];
      for (int i = 0; i < 4; ++i) a[i] = As[k][ty * 4 + i];
      for (int j = 0; j < 4; ++j) bv[j] = Ws[k][tx * 4 + j];
      for (int i = 0; i < 4; ++i)
        for (int j = 0; j < 4; ++j) acc[i][j] += a[i] * bv[j];
    }
    __syncthreads();
  }
  // transpose-stage so the global write is coalesced over l
  for (int i = 0; i < 4; ++i)
    for (int j = 0; j < 4; ++j) ot[tx * 4 + j][ty * 4 + i] = acc[i][j];
  __syncthreads();
  const int b = bm / L_, l0 = bm % L_;
  for (int i = threadIdx.x; i < 64 * 64; i += 256) {
    int cl = i >> 6, ll = i & 63;
    out[((size_t)(b * CDIM + bn + cl)) * L_ + l0 + ll] = ot[cl][ll];
  }
}

extern "C" void kernel_launch(void* const* d_in, const int* in_sizes, int n_in,
                              void* d_out, int out_size, void* d_ws, size_t ws_size,
                              hipStream_t stream) {
  const float* x        = (const float*)d_in[0];
  const float* norm_w   = (const float*)d_in[1];
  const float* norm_b   = (const float*)d_in[2];
  const float* in_w     = (const float*)d_in[3];
  const float* conv_w   = (const float*)d_in[4];
  const float* conv_b   = (const float*)d_in[5];
  const float* xproj_w  = (const float*)d_in[6];
  const float* dt_w     = (const float*)d_in[7];
  const float* dt_b     = (const float*)d_in[8];
  const float* A_log    = (const float*)d_in[9];
  const float* Dp       = (const float*)d_in[10];
  const float* out_w    = (const float*)d_in[11];
  float* out = (float*)d_out;

  const size_t NBL = (size_t)B_ * L_;           // 16384
  float* ws = (float*)d_ws;
  float* xn    = ws;                            // 2,097,152
  float* xin   = xn + NBL * CDIM;               // 4,194,304 (reused as yfin)
  float* z     = xin + NBL * DIN;               // 4,194,304
  float* xc    = z + NBL * DIN;                 // 4,194,304
  float* delta = xc + NBL * DIN;                // 4,194,304
  float* dbl   = delta + NBL * DIN;             // 655,360
  float* P     = dbl + NBL * 40;                // 1,048,576
  float* Q     = P + (size_t)B_ * NC * DIN * DST;
  float* Hin   = Q + (size_t)B_ * NC * DIN * DST;
  float* yfin  = xin;  // xin is dead after k_conv

  k_ln<<<dim3(L_ / 64, B_), 256, 0, stream>>>(x, norm_w, norm_b, xn);
  k_inproj<<<dim3(512 / 64, NBL / 64), 256, 0, stream>>>(xn, in_w, xin, z);
  k_conv<<<(B_ * L_ * DIN) / 256, 256, 0, stream>>>(xin, conv_w, conv_b, xc);
  k_xproj<<<NBL / 16, 256, 0, stream>>>(xc, xproj_w, dbl);
  k_delta<<<(B_ * L_ * DIN) / 256, 256, 0, stream>>>(dbl, dt_w, dt_b, delta);
  k_scan1<<<dim3(NC, B_), 256, 0, stream>>>(delta, xc, dbl, A_log, P, Q);
  k_scan2<<<(B_ * DIN * DST) / 256, 256, 0, stream>>>(P, Q, Hin);
  k_scan3<<<dim3(NC, B_), 256, 0, stream>>>(delta, xc, dbl, A_log, Hin, Dp, z, yfin);
  k_outproj<<<dim3(CDIM / 64, NBL / 64), 256, 0, stream>>>(yfin, out_w, out);
}

// Round 2
// 341.166 us; speedup vs baseline: 1.1129x; 1.1129x over previous
//
#include <hip/hip_runtime.h>
#include <hip/hip_bf16.h>

// Mamba 2D layer, fp32. B=4, C=128, H=W=64 -> L=4096.
// D_INNER=256, D_STATE=16, D_CONV=4, DT_RANK=8.
#define B_ 4
#define CDIM 128
#define L_ 4096
#define DIN 256
#define DST 16
#define DTR 8
#define NC 64   // scan chunks
#define CS 64   // chunk size (L_/NC)

// ---------------- LayerNorm: x (B,C,L) -> xn (B,L,C) ----------------
__global__ __launch_bounds__(256) void k_ln(const float* __restrict__ x,
                                            const float* __restrict__ nw,
                                            const float* __restrict__ nb,
                                            float* __restrict__ xn) {
  const int b = blockIdx.y;
  const int l0 = blockIdx.x * 64;
  __shared__ float xs[64][129];
  __shared__ float mu[64], rs[64];
  for (int i = threadIdx.x; i < CDIM * 64; i += 256) {
    int c = i >> 6, ll = i & 63;           // coalesced over l
    xs[ll][c] = x[((size_t)(b * CDIM + c)) * L_ + l0 + ll];
  }
  __syncthreads();
  if (threadIdx.x < 64) {
    int ll = threadIdx.x;
    float s = 0.f;
    for (int c = 0; c < CDIM; ++c) s += xs[ll][c];
    float m = s * (1.f / CDIM);
    float v = 0.f;
    for (int c = 0; c < CDIM; ++c) { float t = xs[ll][c] - m; v += t * t; }
    mu[ll] = m;
    rs[ll] = rsqrtf(v * (1.f / CDIM) + 1e-5f);
  }
  __syncthreads();
  for (int i = threadIdx.x; i < CDIM * 64; i += 256) {
    int ll = i >> 7, c = i & 127;          // coalesced over c
    float v = (xs[ll][c] - mu[ll]) * rs[ll] * nw[c] + nb[c];
    xn[((size_t)(b * L_ + l0 + ll)) * CDIM + c] = v;
  }
}

// ------------- in_proj: xn (16384,128) @ W(512,128)^T -> xin, z -------------
__global__ __launch_bounds__(256) void k_inproj(const float* __restrict__ A,
                                                const float* __restrict__ W,
                                                float* __restrict__ xin,
                                                float* __restrict__ z) {
  const int bn = blockIdx.x * 64, bm = blockIdx.y * 64;
  __shared__ float As[32][65];
  __shared__ float Ws[32][65];
  float acc[4][4] = {};
  const int tx = threadIdx.x & 15, ty = threadIdx.x >> 4;
  for (int k0 = 0; k0 < 128; k0 += 32) {
    for (int i = threadIdx.x; i < 64 * 32; i += 256) {
      int m = i >> 5, k = i & 31;
      As[k][m] = A[(size_t)(bm + m) * CDIM + k0 + k];
    }
    for (int i = threadIdx.x; i < 64 * 32; i += 256) {
      int n = i >> 5, k = i & 31;
      Ws[k][n] = W[(size_t)(bn + n) * CDIM + k0 + k];
    }
    __syncthreads();
    for (int k = 0; k < 32; ++k) {
      float a[4], bv[4];
      for (int i = 0; i < 4; ++i) a[i] = As[k][ty * 4 + i];
      for (int j = 0; j < 4; ++j) bv[j] = Ws[k][tx * 4 + j];
      for (int i = 0; i < 4; ++i)
        for (int j = 0; j < 4; ++j) acc[i][j] += a[i] * bv[j];
    }
    __syncthreads();
  }
  for (int i = 0; i < 4; ++i) {
    int m = bm + ty * 4 + i;
    for (int j = 0; j < 4; ++j) {
      int n = bn + tx * 4 + j;
      float v = acc[i][j];
      if (n < DIN) xin[(size_t)m * DIN + n] = v;
      else         z[(size_t)m * DIN + (n - DIN)] = v;
    }
  }
}

// ---------------- causal conv (d_conv=4) + SiLU ----------------
__global__ void k_conv(const float* __restrict__ xin, const float* __restrict__ cw,
                       const float* __restrict__ cb, float* __restrict__ xc) {
  int idx = blockIdx.x * 256 + threadIdx.x;
  if (idx >= B_ * L_ * DIN) return;
  int d = idx & 255;
  int bl = idx >> 8;
  int l = bl & (L_ - 1);
  int b = bl >> 12;
  float acc = cb[d];
  for (int k = 0; k < 4; ++k) {
    int ls = l + k - 3;
    float v = (ls >= 0) ? xin[((size_t)(b * L_ + ls)) * DIN + d] : 0.f;
    acc += v * cw[d * 4 + k];
  }
  xc[idx] = acc / (1.f + __expf(-acc));  // silu
}

// ---- x_proj: xc (16384,256) @ W(40,256)^T -> dbl, GEMM w/ 64-wide N tile ----
// N=40 padded to 64 (cols 40..63 computed and discarded). W tile staged in LDS
// so the inner loop has zero global loads (fixes the 76us latency-bound v1).
__global__ __launch_bounds__(256) void k_xproj(const float* __restrict__ xc,
                                               const float* __restrict__ w,
                                               float* __restrict__ dbl) {
  const int bm = blockIdx.x * 64;   // row tile
  __shared__ float As[32][65];
  __shared__ float Ws[32][65];
  float acc[4][4] = {};
  const int tx = threadIdx.x & 15, ty = threadIdx.x >> 4;
  for (int k0 = 0; k0 < DIN; k0 += 32) {
    for (int i = threadIdx.x; i < 64 * 32; i += 256) {
      int m = i >> 5, k = i & 31;
      As[k][m] = xc[(size_t)(bm + m) * DIN + k0 + k];
    }
    for (int i = threadIdx.x; i < 64 * 32; i += 256) {
      int n = i >> 5, k = i & 31;
      Ws[k][n] = (n < 40) ? w[(size_t)n * DIN + k0 + k] : 0.f;
    }
    __syncthreads();
    for (int k = 0; k < 32; ++k) {
      float a[4], bv[4];
      for (int i = 0; i < 4; ++i) a[i] = As[k][ty * 4 + i];
      for (int j = 0; j < 4; ++j) bv[j] = Ws[k][tx * 4 + j];
      for (int i = 0; i < 4; ++i)
        for (int j = 0; j < 4; ++j) acc[i][j] += a[i] * bv[j];
    }
    __syncthreads();
  }
  for (int i = 0; i < 4; ++i) {
    int m = bm + ty * 4 + i;
    for (int j = 0; j < 4; ++j) {
      int n = tx * 4 + j;
      if (n < 40) dbl[(size_t)m * 40 + n] = acc[i][j];
    }
  }
}

// ---------------- delta = softplus(dt @ dt_proj_w^T + b) ----------------
__global__ void k_delta(const float* __restrict__ dbl, const float* __restrict__ w,
                        const float* __restrict__ bias, float* __restrict__ delta) {
  int idx = blockIdx.x * 256 + threadIdx.x;
  if (idx >= B_ * L_ * DIN) return;
  int d = idx & 255;
  size_t bl = idx >> 8;
  const float* dt = dbl + bl * 40;
  const float* wr = w + d * DTR;
  float s = bias[d];
  for (int r = 0; r < DTR; ++r) s += dt[r] * wr[r];
  delta[idx] = (s > 20.f) ? s : __logf(1.f + __expf(s));
}

// ---------------- scan pass 1: per-chunk (P=prod a, Q=partial h) ----------------
__global__ __launch_bounds__(256) void k_scan1(const float* __restrict__ delta,
                                               const float* __restrict__ xc,
                                               const float* __restrict__ dbl,
                                               const float* __restrict__ A_log,
                                               float* __restrict__ P,
                                               float* __restrict__ Q) {
  const int b = blockIdx.y, c = blockIdx.x, d = threadIdx.x;
  const int l0 = c * CS;
  __shared__ float Bs[CS][DST];
  for (int i = threadIdx.x; i < CS * DST; i += 256) {
    int ll = i >> 4, n = i & 15;
    Bs[ll][n] = dbl[((size_t)(b * L_ + l0 + ll)) * 40 + DTR + n];
  }
  float An[DST];
  for (int n = 0; n < DST; ++n) An[n] = -__expf(A_log[d * DST + n]);
  float p[DST], q[DST];
  for (int n = 0; n < DST; ++n) { p[n] = 1.f; q[n] = 0.f; }
  __syncthreads();
  for (int ll = 0; ll < CS; ++ll) {
    size_t bl = (size_t)(b * L_ + l0 + ll);
    float dv = delta[bl * DIN + d];
    float du = dv * xc[bl * DIN + d];
    for (int n = 0; n < DST; ++n) {
      float a = __expf(dv * An[n]);
      p[n] *= a;
      q[n] = a * q[n] + du * Bs[ll][n];
    }
  }
  size_t base = (((size_t)b * NC + c) * DIN + d) * DST;
  for (int n = 0; n < DST; ++n) { P[base + n] = p[n]; Q[base + n] = q[n]; }
}

// ---------------- scan pass 2: sequential combine over chunks ----------------
__global__ void k_scan2(const float* __restrict__ P, const float* __restrict__ Q,
                        float* __restrict__ Hin) {
  int idx = blockIdx.x * 256 + threadIdx.x;  // B*DIN*DST = 16384
  int b = idx / (DIN * DST);
  int dn = idx % (DIN * DST);
  float h = 0.f;
  size_t base = ((size_t)b * NC) * (DIN * DST) + dn;
  float p = P[base], q = Q[base];
  for (int c = 0; c < NC; ++c) {
    size_t nb = base + (size_t)(c + 1) * (DIN * DST);
    float pn = 0.f, qn = 0.f;
    if (c + 1 < NC) { pn = P[nb]; qn = Q[nb]; }
    Hin[base + (size_t)c * (DIN * DST)] = h;
    h = p * h + q;
    p = pn; q = qn;
  }
}

// ---------------- scan pass 3: replay with entry state, fuse D/z-gate ----------------
__global__ __launch_bounds__(256) void k_scan3(const float* __restrict__ delta,
                                               const float* __restrict__ xc,
                                               const float* __restrict__ dbl,
                                               const float* __restrict__ A_log,
                                               const float* __restrict__ Hin,
                                               const float* __restrict__ Dp,
                                               const float* __restrict__ z,
                                               float* __restrict__ yfin) {
  const int b = blockIdx.y, c = blockIdx.x, d = threadIdx.x;
  const int l0 = c * CS;
  __shared__ float Bs[CS][DST], Cs2[CS][DST];
  for (int i = threadIdx.x; i < CS * DST; i += 256) {
    int ll = i >> 4, n = i & 15;
    size_t base = ((size_t)(b * L_ + l0 + ll)) * 40;
    Bs[ll][n]  = dbl[base + DTR + n];
    Cs2[ll][n] = dbl[base + DTR + DST + n];
  }
  float An[DST];
  for (int n = 0; n < DST; ++n) An[n] = -__expf(A_log[d * DST + n]);
  float h[DST];
  size_t hb = (((size_t)b * NC + c) * DIN + d) * DST;
  for (int n = 0; n < DST; ++n) h[n] = Hin[hb + n];
  const float Dd = Dp[d];
  __syncthreads();
  for (int ll = 0; ll < CS; ++ll) {
    size_t bl = (size_t)(b * L_ + l0 + ll);
    float dv = delta[bl * DIN + d];
    float xcv = xc[bl * DIN + d];
    float du = dv * xcv;
    float y = 0.f;
    for (int n = 0; n < DST; ++n) {
      float a = __expf(dv * An[n]);
      h[n] = a * h[n] + du * Bs[ll][n];
      y += h[n] * Cs2[ll][n];
    }
    float zv = z[bl * DIN + d];
    float sz = zv / (1.f + __expf(-zv));
    yfin[bl * DIN + d] = (y + xcv * Dd) * sz;
  }
}

// ------------- out_proj: y (16384,256) @ W(128,256)^T -> out (B,C,L) -------------
__global__ __launch_bounds__(256) void k_outproj(const float* __restrict__ Y,
                                                 const float* __restrict__ W,
                                                 float* __restrict__ out) {
  const int bn = blockIdx.x * 64, bm = blockIdx.y * 64;
  __shared__ float As[32][65];
  __shared__ float Ws[32][65];
  __shared__ float ot[64][65];
  float acc[4][4] = {};
  const int tx = threadIdx.x & 15, ty = threadIdx.x >> 4;
  for (int k0 = 0; k0 < DIN; k0 += 32) {
    for (int i = threadIdx.x; i < 64 * 32; i += 256) {
      int m = i >> 5, k = i & 31;
      As[k][m] = Y[(size_t)(bm + m) * DIN + k0 + k];
    }
    for (int i = threadIdx.x; i < 64 * 32; i += 256) {
      int n = i >> 5, k = i & 31;
      Ws[k][n] = W[(size_t)(bn + n) * DIN + k0 + k];
    }
    __syncthreads();
    for (int k = 0; k < 32; ++k) {
      float a[4], bv[4];
      for (int i = 0; i < 4; ++i) a[i] = As[k][ty * 4 + i];
      for (int j = 0; j < 4; ++j) bv[j] = Ws[k][tx * 4 + j];
      for (int i = 0; i < 4; ++i)
        for (int j = 0; j < 4; ++j) acc[i][j] += a[i] * bv[j];
    }
    __syncthreads();
  }
  // transpose-stage so the global write is coalesced over l
  for (int i = 0; i < 4; ++i)
    for (int j = 0; j < 4; ++j) ot[tx * 4 + j][ty * 4 + i] = acc[i][j];
  __syncthreads();
  const int b = bm / L_, l0 = bm % L_;
  for (int i = threadIdx.x; i < 64 * 64; i += 256) {
    int cl = i >> 6, ll = i & 63;
    out[((size_t)(b * CDIM + bn + cl)) * L_ + l0 + ll] = ot[cl][ll];
  }
}

extern "C" void kernel_launch(void* const* d_in, const int* in_sizes, int n_in,
                              void* d_out, int out_size, void* d_ws, size_t ws_size,
                              hipStream_t stream) {
  const float* x        = (const float*)d_in[0];
  const float* norm_w   = (const float*)d_in[1];
  const float* norm_b   = (const float*)d_in[2];
  const float* in_w     = (const float*)d_in[3];
  const float* conv_w   = (const float*)d_in[4];
  const float* conv_b   = (const float*)d_in[5];
  const float* xproj_w  = (const float*)d_in[6];
  const float* dt_w     = (const float*)d_in[7];
  const float* dt_b     = (const float*)d_in[8];
  const float* A_log    = (const float*)d_in[9];
  const float* Dp       = (const float*)d_in[10];
  const float* out_w    = (const float*)d_in[11];
  float* out = (float*)d_out;

  const size_t NBL = (size_t)B_ * L_;           // 16384
  float* ws = (float*)d_ws;
  float* xn    = ws;                            // 2,097,152
  float* xin   = xn + NBL * CDIM;               // 4,194,304 (reused as yfin)
  float* z     = xin + NBL * DIN;               // 4,194,304
  float* xc    = z + NBL * DIN;                 // 4,194,304
  float* delta = xc + NBL * DIN;                // 4,194,304
  float* dbl   = delta + NBL * DIN;             // 655,360
  float* P     = dbl + NBL * 40;                // 1,048,576
  float* Q     = P + (size_t)B_ * NC * DIN * DST;
  float* Hin   = Q + (size_t)B_ * NC * DIN * DST;
  float* yfin  = xin;  // xin is dead after k_conv

  k_ln<<<dim3(L_ / 64, B_), 256, 0, stream>>>(x, norm_w, norm_b, xn);
  k_inproj<<<dim3(512 / 64, NBL / 64), 256, 0, stream>>>(xn, in_w, xin, z);
  k_conv<<<(B_ * L_ * DIN) / 256, 256, 0, stream>>>(xin, conv_w, conv_b, xc);
  k_xproj<<<NBL / 64, 256, 0, stream>>>(xc, xproj_w, dbl);
  k_delta<<<(B_ * L_ * DIN) / 256, 256, 0, stream>>>(dbl, dt_w, dt_b, delta);
  k_scan1<<<dim3(NC, B_), 256, 0, stream>>>(delta, xc, dbl, A_log, P, Q);
  k_scan2<<<(B_ * DIN * DST) / 256, 256, 0, stream>>>(P, Q, Hin);
  k_scan3<<<dim3(NC, B_), 256, 0, stream>>>(delta, xc, dbl, A_log, Hin, Dp, z, yfin);
  k_outproj<<<dim3(CDIM / 64, NBL / 64), 256, 0, stream>>>(yfin, out_w, out);
}

// Round 3
// 323.126 us; speedup vs baseline: 1.1750x; 1.0558x over previous
//
#include <hip/hip_runtime.h>
#include <hip/hip_bf16.h>

// Mamba 2D layer, fp32. B=4, C=128, H=W=64 -> L=4096.
// D_INNER=256, D_STATE=16, D_CONV=4, DT_RANK=8.
#define B_ 4
#define CDIM 128
#define L_ 4096
#define DIN 256
#define DST 16
#define DTR 8
#define NC 64   // scan chunks
#define CS 64   // chunk size (L_/NC)

// ---------------- LayerNorm: x (B,C,L) -> xn (B,L,C) ----------------
__global__ __launch_bounds__(256) void k_ln(const float* __restrict__ x,
                                            const float* __restrict__ nw,
                                            const float* __restrict__ nb,
                                            float* __restrict__ xn) {
  const int b = blockIdx.y;
  const int l0 = blockIdx.x * 64;
  __shared__ float xs[64][129];
  __shared__ float mu[64], rs[64];
  for (int i = threadIdx.x; i < CDIM * 64; i += 256) {
    int c = i >> 6, ll = i & 63;           // coalesced over l
    xs[ll][c] = x[((size_t)(b * CDIM + c)) * L_ + l0 + ll];
  }
  __syncthreads();
  if (threadIdx.x < 64) {
    int ll = threadIdx.x;
    float s = 0.f;
    for (int c = 0; c < CDIM; ++c) s += xs[ll][c];
    float m = s * (1.f / CDIM);
    float v = 0.f;
    for (int c = 0; c < CDIM; ++c) { float t = xs[ll][c] - m; v += t * t; }
    mu[ll] = m;
    rs[ll] = rsqrtf(v * (1.f / CDIM) + 1e-5f);
  }
  __syncthreads();
  for (int i = threadIdx.x; i < CDIM * 64; i += 256) {
    int ll = i >> 7, c = i & 127;          // coalesced over c
    float v = (xs[ll][c] - mu[ll]) * rs[ll] * nw[c] + nb[c];
    xn[((size_t)(b * L_ + l0 + ll)) * CDIM + c] = v;
  }
}

// ------------- in_proj: xn (16384,128) @ W(512,128)^T -> xin, z -------------
// 128x128 tile, 8x8 per-thread regs. A in LDS m-major stride 20 with XOR-k
// swizzle (4 ty-lanes -> 4 banks), W in LDS k-major stride 132 (b128 reads).
// XCD-swizzled grid: each XCD owns all 4 N-tiles of its 16 M-tiles so A is
// fetched from HBM once per XCD (was 4x = 33MB FETCH).
__global__ __launch_bounds__(256) void k_inproj(const float* __restrict__ A,
                                                const float* __restrict__ W,
                                                float* __restrict__ xin,
                                                float* __restrict__ z) {
  const int bid = blockIdx.x;        // 512 blocks
  const int xcd = bid & 7, slot = bid >> 3;
  const int bm = (xcd * 16 + (slot >> 2)) * 128;
  const int bn = (slot & 3) * 128;
  __shared__ float As[128 * 20];
  __shared__ float Ws[16 * 132];
  const int tid = threadIdx.x;
  const int tx = tid & 15, ty = tid >> 4;
  const int swz = (ty & 3) * 4;
  float acc[8][8] = {};
  for (int k0 = 0; k0 < CDIM; k0 += 16) {
    for (int t = 0; t < 2; ++t) {
      int f = tid + t * 256;
      int r = f >> 2, kq = f & 3;
      float4 v = *reinterpret_cast<const float4*>(A + (size_t)(bm + r) * CDIM + k0 + kq * 4);
      int kk = (kq * 4) ^ (((r >> 3) & 3) * 4);
      *reinterpret_cast<float4*>(&As[r * 20 + kk]) = v;
    }
    for (int t = 0; t < 2; ++t) {
      int f = tid + t * 256;
      int n = f >> 2, kq = f & 3;
      float4 v = *reinterpret_cast<const float4*>(W + (size_t)(bn + n) * CDIM + k0 + kq * 4);
      Ws[(kq * 4 + 0) * 132 + n] = v.x;
      Ws[(kq * 4 + 1) * 132 + n] = v.y;
      Ws[(kq * 4 + 2) * 132 + n] = v.z;
      Ws[(kq * 4 + 3) * 132 + n] = v.w;
    }
    __syncthreads();
#pragma unroll 4
    for (int k = 0; k < 16; ++k) {
      const int ks = k ^ swz;
      float a[8], b[8];
#pragma unroll
      for (int i = 0; i < 8; ++i) a[i] = As[(ty * 8 + i) * 20 + ks];
      float4 b0 = *reinterpret_cast<const float4*>(&Ws[k * 132 + tx * 8]);
      float4 b1 = *reinterpret_cast<const float4*>(&Ws[k * 132 + tx * 8 + 4]);
      b[0] = b0.x; b[1] = b0.y; b[2] = b0.z; b[3] = b0.w;
      b[4] = b1.x; b[5] = b1.y; b[6] = b1.z; b[7] = b1.w;
#pragma unroll
      for (int i = 0; i < 8; ++i)
#pragma unroll
        for (int j = 0; j < 8; ++j) acc[i][j] += a[i] * b[j];
    }
    __syncthreads();
  }
  float* dst = (bn < DIN) ? xin : z;
  const int nc0 = (bn < DIN) ? bn : bn - DIN;
  for (int i = 0; i < 8; ++i) {
    size_t m = bm + ty * 8 + i;
    float4 v0 = {acc[i][0], acc[i][1], acc[i][2], acc[i][3]};
    float4 v1 = {acc[i][4], acc[i][5], acc[i][6], acc[i][7]};
    *reinterpret_cast<float4*>(dst + m * DIN + nc0 + tx * 8)     = v0;
    *reinterpret_cast<float4*>(dst + m * DIN + nc0 + tx * 8 + 4) = v1;
  }
}

// ---------------- causal conv (d_conv=4) + SiLU ----------------
__global__ void k_conv(const float* __restrict__ xin, const float* __restrict__ cw,
                       const float* __restrict__ cb, float* __restrict__ xc) {
  int idx = blockIdx.x * 256 + threadIdx.x;
  if (idx >= B_ * L_ * DIN) return;
  int d = idx & 255;
  int bl = idx >> 8;
  int l = bl & (L_ - 1);
  int b = bl >> 12;
  float acc = cb[d];
  for (int k = 0; k < 4; ++k) {
    int ls = l + k - 3;
    float v = (ls >= 0) ? xin[((size_t)(b * L_ + ls)) * DIN + d] : 0.f;
    acc += v * cw[d * 4 + k];
  }
  xc[idx] = acc / (1.f + __expf(-acc));  // silu
}

// ---- x_proj: xc (16384,256) @ W(40,256)^T -> dbl, GEMM w/ 64-wide N tile ----
__global__ __launch_bounds__(256) void k_xproj(const float* __restrict__ xc,
                                               const float* __restrict__ w,
                                               float* __restrict__ dbl) {
  const int bm = blockIdx.x * 64;   // row tile
  __shared__ float As[32][65];
  __shared__ float Ws[32][65];
  float acc[4][4] = {};
  const int tx = threadIdx.x & 15, ty = threadIdx.x >> 4;
  for (int k0 = 0; k0 < DIN; k0 += 32) {
    for (int i = threadIdx.x; i < 64 * 32; i += 256) {
      int m = i >> 5, k = i & 31;
      As[k][m] = xc[(size_t)(bm + m) * DIN + k0 + k];
    }
    for (int i = threadIdx.x; i < 64 * 32; i += 256) {
      int n = i >> 5, k = i & 31;
      Ws[k][n] = (n < 40) ? w[(size_t)n * DIN + k0 + k] : 0.f;
    }
    __syncthreads();
    for (int k = 0; k < 32; ++k) {
      float a[4], bv[4];
      for (int i = 0; i < 4; ++i) a[i] = As[k][ty * 4 + i];
      for (int j = 0; j < 4; ++j) bv[j] = Ws[k][tx * 4 + j];
      for (int i = 0; i < 4; ++i)
        for (int j = 0; j < 4; ++j) acc[i][j] += a[i] * bv[j];
    }
    __syncthreads();
  }
  for (int i = 0; i < 4; ++i) {
    int m = bm + ty * 4 + i;
    for (int j = 0; j < 4; ++j) {
      int n = tx * 4 + j;
      if (n < 40) dbl[(size_t)m * 40 + n] = acc[i][j];
    }
  }
}

// ---------------- delta = softplus(dt @ dt_proj_w^T + b) ----------------
__global__ void k_delta(const float* __restrict__ dbl, const float* __restrict__ w,
                        const float* __restrict__ bias, float* __restrict__ delta) {
  int idx = blockIdx.x * 256 + threadIdx.x;
  if (idx >= B_ * L_ * DIN) return;
  int d = idx & 255;
  size_t bl = idx >> 8;
  const float* dt = dbl + bl * 40;
  const float* wr = w + d * DTR;
  float s = bias[d];
  for (int r = 0; r < DTR; ++r) s += dt[r] * wr[r];
  delta[idx] = (s > 20.f) ? s : __logf(1.f + __expf(s));
}

// ---------------- scan pass 1: per-chunk (P=prod a, Q=partial h) ----------------
__global__ __launch_bounds__(256) void k_scan1(const float* __restrict__ delta,
                                               const float* __restrict__ xc,
                                               const float* __restrict__ dbl,
                                               const float* __restrict__ A_log,
                                               float* __restrict__ P,
                                               float* __restrict__ Q) {
  const int b = blockIdx.y, c = blockIdx.x, d = threadIdx.x;
  const int l0 = c * CS;
  __shared__ float Bs[CS][DST];
  for (int i = threadIdx.x; i < CS * DST; i += 256) {
    int ll = i >> 4, n = i & 15;
    Bs[ll][n] = dbl[((size_t)(b * L_ + l0 + ll)) * 40 + DTR + n];
  }
  float An[DST];
  for (int n = 0; n < DST; ++n) An[n] = -__expf(A_log[d * DST + n]);
  float p[DST], q[DST];
  for (int n = 0; n < DST; ++n) { p[n] = 1.f; q[n] = 0.f; }
  __syncthreads();
  for (int ll = 0; ll < CS; ++ll) {
    size_t bl = (size_t)(b * L_ + l0 + ll);
    float dv = delta[bl * DIN + d];
    float du = dv * xc[bl * DIN + d];
    for (int n = 0; n < DST; ++n) {
      float a = __expf(dv * An[n]);
      p[n] *= a;
      q[n] = a * q[n] + du * Bs[ll][n];
    }
  }
  size_t base = (((size_t)b * NC + c) * DIN + d) * DST;
  for (int n = 0; n < DST; ++n) { P[base + n] = p[n]; Q[base + n] = q[n]; }
}

// ---------------- scan pass 2: sequential combine over chunks ----------------
__global__ void k_scan2(const float* __restrict__ P, const float* __restrict__ Q,
                        float* __restrict__ Hin) {
  int idx = blockIdx.x * 256 + threadIdx.x;  // B*DIN*DST = 16384
  int b = idx / (DIN * DST);
  int dn = idx % (DIN * DST);
  float h = 0.f;
  size_t base = ((size_t)b * NC) * (DIN * DST) + dn;
  float p = P[base], q = Q[base];
  for (int c = 0; c < NC; ++c) {
    size_t nb = base + (size_t)(c + 1) * (DIN * DST);
    float pn = 0.f, qn = 0.f;
    if (c + 1 < NC) { pn = P[nb]; qn = Q[nb]; }
    Hin[base + (size_t)c * (DIN * DST)] = h;
    h = p * h + q;
    p = pn; q = qn;
  }
}

// ---------------- scan pass 3: replay with entry state, fuse D/z-gate ----------------
__global__ __launch_bounds__(256) void k_scan3(const float* __restrict__ delta,
                                               const float* __restrict__ xc,
                                               const float* __restrict__ dbl,
                                               const float* __restrict__ A_log,
                                               const float* __restrict__ Hin,
                                               const float* __restrict__ Dp,
                                               const float* __restrict__ z,
                                               float* __restrict__ yfin) {
  const int b = blockIdx.y, c = blockIdx.x, d = threadIdx.x;
  const int l0 = c * CS;
  __shared__ float Bs[CS][DST], Cs2[CS][DST];
  for (int i = threadIdx.x; i < CS * DST; i += 256) {
    int ll = i >> 4, n = i & 15;
    size_t base = ((size_t)(b * L_ + l0 + ll)) * 40;
    Bs[ll][n]  = dbl[base + DTR + n];
    Cs2[ll][n] = dbl[base + DTR + DST + n];
  }
  float An[DST];
  for (int n = 0; n < DST; ++n) An[n] = -__expf(A_log[d * DST + n]);
  float h[DST];
  size_t hb = (((size_t)b * NC + c) * DIN + d) * DST;
  for (int n = 0; n < DST; ++n) h[n] = Hin[hb + n];
  const float Dd = Dp[d];
  __syncthreads();
  for (int ll = 0; ll < CS; ++ll) {
    size_t bl = (size_t)(b * L_ + l0 + ll);
    float dv = delta[bl * DIN + d];
    float xcv = xc[bl * DIN + d];
    float du = dv * xcv;
    float y = 0.f;
    for (int n = 0; n < DST; ++n) {
      float a = __expf(dv * An[n]);
      h[n] = a * h[n] + du * Bs[ll][n];
      y += h[n] * Cs2[ll][n];
    }
    float zv = z[bl * DIN + d];
    float sz = zv / (1.f + __expf(-zv));
    yfin[bl * DIN + d] = (y + xcv * Dd) * sz;
  }
}

// ------------- out_proj: y (16384,256) @ W(128,256)^T -> out (B,C,L) -------------
// Same 128x128 / 8x8 structure; K=256, N=128 (grid = M/128 blocks).
// Epilogue writes transposed directly: 4 ty-lanes give 128B contiguous per
// output row (coalesced over l), no LDS round-trip.
__global__ __launch_bounds__(256) void k_outproj(const float* __restrict__ Y,
                                                 const float* __restrict__ W,
                                                 float* __restrict__ out) {
  const int bm = blockIdx.x * 128;
  __shared__ float As[128 * 20];
  __shared__ float Ws[16 * 132];
  const int tid = threadIdx.x;
  const int tx = tid & 15, ty = tid >> 4;
  const int swz = (ty & 3) * 4;
  float acc[8][8] = {};
  for (int k0 = 0; k0 < DIN; k0 += 16) {
    for (int t = 0; t < 2; ++t) {
      int f = tid + t * 256;
      int r = f >> 2, kq = f & 3;
      float4 v = *reinterpret_cast<const float4*>(Y + (size_t)(bm + r) * DIN + k0 + kq * 4);
      int kk = (kq * 4) ^ (((r >> 3) & 3) * 4);
      *reinterpret_cast<float4*>(&As[r * 20 + kk]) = v;
    }
    for (int t = 0; t < 2; ++t) {
      int f = tid + t * 256;
      int n = f >> 2, kq = f & 3;
      float4 v = *reinterpret_cast<const float4*>(W + (size_t)n * DIN + k0 + kq * 4);
      Ws[(kq * 4 + 0) * 132 + n] = v.x;
      Ws[(kq * 4 + 1) * 132 + n] = v.y;
      Ws[(kq * 4 + 2) * 132 + n] = v.z;
      Ws[(kq * 4 + 3) * 132 + n] = v.w;
    }
    __syncthreads();
#pragma unroll 4
    for (int k = 0; k < 16; ++k) {
      const int ks = k ^ swz;
      float a[8], b[8];
#pragma unroll
      for (int i = 0; i < 8; ++i) a[i] = As[(ty * 8 + i) * 20 + ks];
      float4 b0 = *reinterpret_cast<const float4*>(&Ws[k * 132 + tx * 8]);
      float4 b1 = *reinterpret_cast<const float4*>(&Ws[k * 132 + tx * 8 + 4]);
      b[0] = b0.x; b[1] = b0.y; b[2] = b0.z; b[3] = b0.w;
      b[4] = b1.x; b[5] = b1.y; b[6] = b1.z; b[7] = b1.w;
#pragma unroll
      for (int i = 0; i < 8; ++i)
#pragma unroll
        for (int j = 0; j < 8; ++j) acc[i][j] += a[i] * b[j];
    }
    __syncthreads();
  }
  const int b = bm >> 12;        // bm / L_
  const int l0 = bm & (L_ - 1);
#pragma unroll
  for (int j = 0; j < 8; ++j) {
    int n = tx * 8 + j;
    size_t row = ((size_t)(b * CDIM + n)) * L_ + l0 + ty * 8;
    float4 v0 = {acc[0][j], acc[1][j], acc[2][j], acc[3][j]};
    float4 v1 = {acc[4][j], acc[5][j], acc[6][j], acc[7][j]};
    *reinterpret_cast<float4*>(out + row)     = v0;
    *reinterpret_cast<float4*>(out + row + 4) = v1;
  }
}

extern "C" void kernel_launch(void* const* d_in, const int* in_sizes, int n_in,
                              void* d_out, int out_size, void* d_ws, size_t ws_size,
                              hipStream_t stream) {
  const float* x        = (const float*)d_in[0];
  const float* norm_w   = (const float*)d_in[1];
  const float* norm_b   = (const float*)d_in[2];
  const float* in_w     = (const float*)d_in[3];
  const float* conv_w   = (const float*)d_in[4];
  const float* conv_b   = (const float*)d_in[5];
  const float* xproj_w  = (const float*)d_in[6];
  const float* dt_w     = (const float*)d_in[7];
  const float* dt_b     = (const float*)d_in[8];
  const float* A_log    = (const float*)d_in[9];
  const float* Dp       = (const float*)d_in[10];
  const float* out_w    = (const float*)d_in[11];
  float* out = (float*)d_out;

  const size_t NBL = (size_t)B_ * L_;           // 16384
  float* ws = (float*)d_ws;
  float* xn    = ws;                            // 2,097,152
  float* xin   = xn + NBL * CDIM;               // 4,194,304 (reused as yfin)
  float* z     = xin + NBL * DIN;               // 4,194,304
  float* xc    = z + NBL * DIN;                 // 4,194,304
  float* delta = xc + NBL * DIN;                // 4,194,304
  float* dbl   = delta + NBL * DIN;             // 655,360
  float* P     = dbl + NBL * 40;                // 1,048,576
  float* Q     = P + (size_t)B_ * NC * DIN * DST;
  float* Hin   = Q + (size_t)B_ * NC * DIN * DST;
  float* yfin  = xin;  // xin is dead after k_conv

  k_ln<<<dim3(L_ / 64, B_), 256, 0, stream>>>(x, norm_w, norm_b, xn);
  k_inproj<<<512, 256, 0, stream>>>(xn, in_w, xin, z);
  k_conv<<<(B_ * L_ * DIN) / 256, 256, 0, stream>>>(xin, conv_w, conv_b, xc);
  k_xproj<<<NBL / 64, 256, 0, stream>>>(xc, xproj_w, dbl);
  k_delta<<<(B_ * L_ * DIN) / 256, 256, 0, stream>>>(dbl, dt_w, dt_b, delta);
  k_scan1<<<dim3(NC, B_), 256, 0, stream>>>(delta, xc, dbl, A_log, P, Q);
  k_scan2<<<(B_ * DIN * DST) / 256, 256, 0, stream>>>(P, Q, Hin);
  k_scan3<<<dim3(NC, B_), 256, 0, stream>>>(delta, xc, dbl, A_log, Hin, Dp, z, yfin);
  k_outproj<<<CDIM / 128 * (NBL / 128), 256, 0, stream>>>(yfin, out_w, out);
}

// Round 4
// 314.646 us; speedup vs baseline: 1.2067x; 1.0270x over previous
//
#include <hip/hip_runtime.h>
#include <hip/hip_bf16.h>

// Mamba 2D layer, fp32. B=4, C=128, H=W=64 -> L=4096.
// D_INNER=256, D_STATE=16, D_CONV=4, DT_RANK=8.
#define B_ 4
#define CDIM 128
#define L_ 4096
#define DIN 256
#define DST 16
#define DTR 8
#define NC 64   // scan chunks
#define CS 64   // chunk size (L_/NC)

// ---------------- LayerNorm: x (B,C,L) -> xn (B,L,C) ----------------
__global__ __launch_bounds__(256) void k_ln(const float* __restrict__ x,
                                            const float* __restrict__ nw,
                                            const float* __restrict__ nb,
                                            float* __restrict__ xn) {
  const int b = blockIdx.y;
  const int l0 = blockIdx.x * 64;
  __shared__ float xs[64][129];
  __shared__ float mu[64], rs[64];
  for (int i = threadIdx.x; i < CDIM * 64; i += 256) {
    int c = i >> 6, ll = i & 63;           // coalesced over l
    xs[ll][c] = x[((size_t)(b * CDIM + c)) * L_ + l0 + ll];
  }
  __syncthreads();
  if (threadIdx.x < 64) {
    int ll = threadIdx.x;
    float s = 0.f;
    for (int c = 0; c < CDIM; ++c) s += xs[ll][c];
    float m = s * (1.f / CDIM);
    float v = 0.f;
    for (int c = 0; c < CDIM; ++c) { float t = xs[ll][c] - m; v += t * t; }
    mu[ll] = m;
    rs[ll] = rsqrtf(v * (1.f / CDIM) + 1e-5f);
  }
  __syncthreads();
  for (int i = threadIdx.x; i < CDIM * 64; i += 256) {
    int ll = i >> 7, c = i & 127;          // coalesced over c
    float v = (xs[ll][c] - mu[ll]) * rs[ll] * nw[c] + nb[c];
    xn[((size_t)(b * L_ + l0 + ll)) * CDIM + c] = v;
  }
}

// ------------- in_proj: xn (16384,128) @ W(512,128)^T -> xin, z -------------
// 128x128 tile, 8x8 per-thread regs, XCD-swizzled grid (A fetched once/XCD).
__global__ __launch_bounds__(256) void k_inproj(const float* __restrict__ A,
                                                const float* __restrict__ W,
                                                float* __restrict__ xin,
                                                float* __restrict__ z) {
  const int bid = blockIdx.x;        // 512 blocks
  const int xcd = bid & 7, slot = bid >> 3;
  const int bm = (xcd * 16 + (slot >> 2)) * 128;
  const int bn = (slot & 3) * 128;
  __shared__ float As[128 * 20];
  __shared__ float Ws[16 * 132];
  const int tid = threadIdx.x;
  const int tx = tid & 15, ty = tid >> 4;
  const int swz = (ty & 3) * 4;
  float acc[8][8] = {};
  for (int k0 = 0; k0 < CDIM; k0 += 16) {
    for (int t = 0; t < 2; ++t) {
      int f = tid + t * 256;
      int r = f >> 2, kq = f & 3;
      float4 v = *reinterpret_cast<const float4*>(A + (size_t)(bm + r) * CDIM + k0 + kq * 4);
      int kk = (kq * 4) ^ (((r >> 3) & 3) * 4);
      *reinterpret_cast<float4*>(&As[r * 20 + kk]) = v;
    }
    for (int t = 0; t < 2; ++t) {
      int f = tid + t * 256;
      int n = f >> 2, kq = f & 3;
      float4 v = *reinterpret_cast<const float4*>(W + (size_t)(bn + n) * CDIM + k0 + kq * 4);
      Ws[(kq * 4 + 0) * 132 + n] = v.x;
      Ws[(kq * 4 + 1) * 132 + n] = v.y;
      Ws[(kq * 4 + 2) * 132 + n] = v.z;
      Ws[(kq * 4 + 3) * 132 + n] = v.w;
    }
    __syncthreads();
#pragma unroll 4
    for (int k = 0; k < 16; ++k) {
      const int ks = k ^ swz;
      float a[8], b[8];
#pragma unroll
      for (int i = 0; i < 8; ++i) a[i] = As[(ty * 8 + i) * 20 + ks];
      float4 b0 = *reinterpret_cast<const float4*>(&Ws[k * 132 + tx * 8]);
      float4 b1 = *reinterpret_cast<const float4*>(&Ws[k * 132 + tx * 8 + 4]);
      b[0] = b0.x; b[1] = b0.y; b[2] = b0.z; b[3] = b0.w;
      b[4] = b1.x; b[5] = b1.y; b[6] = b1.z; b[7] = b1.w;
#pragma unroll
      for (int i = 0; i < 8; ++i)
#pragma unroll
        for (int j = 0; j < 8; ++j) acc[i][j] += a[i] * b[j];
    }
    __syncthreads();
  }
  float* dst = (bn < DIN) ? xin : z;
  const int nc0 = (bn < DIN) ? bn : bn - DIN;
  for (int i = 0; i < 8; ++i) {
    size_t m = bm + ty * 8 + i;
    float4 v0 = {acc[i][0], acc[i][1], acc[i][2], acc[i][3]};
    float4 v1 = {acc[i][4], acc[i][5], acc[i][6], acc[i][7]};
    *reinterpret_cast<float4*>(dst + m * DIN + nc0 + tx * 8)     = v0;
    *reinterpret_cast<float4*>(dst + m * DIN + nc0 + tx * 8 + 4) = v1;
  }
}

// ---------------- causal conv (d_conv=4) + SiLU ----------------
__global__ void k_conv(const float* __restrict__ xin, const float* __restrict__ cw,
                       const float* __restrict__ cb, float* __restrict__ xc) {
  int idx = blockIdx.x * 256 + threadIdx.x;
  if (idx >= B_ * L_ * DIN) return;
  int d = idx & 255;
  int bl = idx >> 8;
  int l = bl & (L_ - 1);
  int b = bl >> 12;
  float acc = cb[d];
  for (int k = 0; k < 4; ++k) {
    int ls = l + k - 3;
    float v = (ls >= 0) ? xin[((size_t)(b * L_ + ls)) * DIN + d] : 0.f;
    acc += v * cw[d * 4 + k];
  }
  xc[idx] = acc / (1.f + __expf(-acc));  // silu
}

// ---- x_proj: xc (16384,256) @ W(40,256)^T -> dbl, GEMM w/ 64-wide N tile ----
__global__ __launch_bounds__(256) void k_xproj(const float* __restrict__ xc,
                                               const float* __restrict__ w,
                                               float* __restrict__ dbl) {
  const int bm = blockIdx.x * 64;   // row tile
  __shared__ float As[32][65];
  __shared__ float Ws[32][65];
  float acc[4][4] = {};
  const int tx = threadIdx.x & 15, ty = threadIdx.x >> 4;
  for (int k0 = 0; k0 < DIN; k0 += 32) {
    for (int i = threadIdx.x; i < 64 * 32; i += 256) {
      int m = i >> 5, k = i & 31;
      As[k][m] = xc[(size_t)(bm + m) * DIN + k0 + k];
    }
    for (int i = threadIdx.x; i < 64 * 32; i += 256) {
      int n = i >> 5, k = i & 31;
      Ws[k][n] = (n < 40) ? w[(size_t)n * DIN + k0 + k] : 0.f;
    }
    __syncthreads();
    for (int k = 0; k < 32; ++k) {
      float a[4], bv[4];
      for (int i = 0; i < 4; ++i) a[i] = As[k][ty * 4 + i];
      for (int j = 0; j < 4; ++j) bv[j] = Ws[k][tx * 4 + j];
      for (int i = 0; i < 4; ++i)
        for (int j = 0; j < 4; ++j) acc[i][j] += a[i] * bv[j];
    }
    __syncthreads();
  }
  for (int i = 0; i < 4; ++i) {
    int m = bm + ty * 4 + i;
    for (int j = 0; j < 4; ++j) {
      int n = tx * 4 + j;
      if (n < 40) dbl[(size_t)m * 40 + n] = acc[i][j];
    }
  }
}

// -------- scan pass 1 (delta fused): per-chunk (P=prod a, Q=partial h) --------
__global__ __launch_bounds__(256) void k_scan1(const float* __restrict__ xc,
                                               const float* __restrict__ dbl,
                                               const float* __restrict__ dtw,
                                               const float* __restrict__ dtb,
                                               const float* __restrict__ A_log,
                                               float* __restrict__ P,
                                               float* __restrict__ Q) {
  const int b = blockIdx.y, c = blockIdx.x, d = threadIdx.x;
  const int l0 = c * CS;
  __shared__ float Bs[CS][DST];
  __shared__ float Ds[CS][DTR];
  for (int i = threadIdx.x; i < CS * DST; i += 256) {
    int ll = i >> 4, n = i & 15;
    Bs[ll][n] = dbl[((size_t)(b * L_ + l0 + ll)) * 40 + DTR + n];
  }
  for (int i = threadIdx.x; i < CS * DTR; i += 256) {
    int ll = i >> 3, r = i & 7;
    Ds[ll][r] = dbl[((size_t)(b * L_ + l0 + ll)) * 40 + r];
  }
  float An[DST];
  for (int n = 0; n < DST; ++n) An[n] = -__expf(A_log[d * DST + n]);
  float wr[DTR];
  for (int r = 0; r < DTR; ++r) wr[r] = dtw[d * DTR + r];
  const float bias = dtb[d];
  float p[DST], q[DST];
  for (int n = 0; n < DST; ++n) { p[n] = 1.f; q[n] = 0.f; }
  __syncthreads();
  for (int ll = 0; ll < CS; ++ll) {
    size_t bl = (size_t)(b * L_ + l0 + ll);
    float s = bias;
#pragma unroll
    for (int r = 0; r < DTR; ++r) s += Ds[ll][r] * wr[r];
    float dv = (s > 20.f) ? s : __logf(1.f + __expf(s));
    float du = dv * xc[bl * DIN + d];
#pragma unroll
    for (int n = 0; n < DST; ++n) {
      float a = __expf(dv * An[n]);
      p[n] *= a;
      q[n] = a * q[n] + du * Bs[ll][n];
    }
  }
  size_t base = (((size_t)b * NC + c) * DIN + d) * DST;
  for (int n = 0; n < DST; ++n) { P[base + n] = p[n]; Q[base + n] = q[n]; }
}

// ---------------- scan pass 2: sequential combine over chunks ----------------
__global__ void k_scan2(const float* __restrict__ P, const float* __restrict__ Q,
                        float* __restrict__ Hin) {
  int idx = blockIdx.x * 256 + threadIdx.x;  // B*DIN*DST = 16384
  int b = idx / (DIN * DST);
  int dn = idx % (DIN * DST);
  float h = 0.f;
  size_t base = ((size_t)b * NC) * (DIN * DST) + dn;
  float p = P[base], q = Q[base];
  for (int c = 0; c < NC; ++c) {
    size_t nb = base + (size_t)(c + 1) * (DIN * DST);
    float pn = 0.f, qn = 0.f;
    if (c + 1 < NC) { pn = P[nb]; qn = Q[nb]; }
    Hin[base + (size_t)c * (DIN * DST)] = h;
    h = p * h + q;
    p = pn; q = qn;
  }
}

// -------- scan pass 3 (delta fused): replay w/ entry state, D/z-gate --------
__global__ __launch_bounds__(256) void k_scan3(const float* __restrict__ xc,
                                               const float* __restrict__ dbl,
                                               const float* __restrict__ dtw,
                                               const float* __restrict__ dtb,
                                               const float* __restrict__ A_log,
                                               const float* __restrict__ Hin,
                                               const float* __restrict__ Dp,
                                               const float* __restrict__ z,
                                               float* __restrict__ yfin) {
  const int b = blockIdx.y, c = blockIdx.x, d = threadIdx.x;
  const int l0 = c * CS;
  __shared__ float Bs[CS][DST], Cs2[CS][DST];
  __shared__ float Ds[CS][DTR];
  for (int i = threadIdx.x; i < CS * DST; i += 256) {
    int ll = i >> 4, n = i & 15;
    size_t base = ((size_t)(b * L_ + l0 + ll)) * 40;
    Bs[ll][n]  = dbl[base + DTR + n];
    Cs2[ll][n] = dbl[base + DTR + DST + n];
  }
  for (int i = threadIdx.x; i < CS * DTR; i += 256) {
    int ll = i >> 3, r = i & 7;
    Ds[ll][r] = dbl[((size_t)(b * L_ + l0 + ll)) * 40 + r];
  }
  float An[DST];
  for (int n = 0; n < DST; ++n) An[n] = -__expf(A_log[d * DST + n]);
  float wr[DTR];
  for (int r = 0; r < DTR; ++r) wr[r] = dtw[d * DTR + r];
  const float bias = dtb[d];
  float h[DST];
  size_t hb = (((size_t)b * NC + c) * DIN + d) * DST;
  for (int n = 0; n < DST; ++n) h[n] = Hin[hb + n];
  const float Dd = Dp[d];
  __syncthreads();
  for (int ll = 0; ll < CS; ++ll) {
    size_t bl = (size_t)(b * L_ + l0 + ll);
    float s = bias;
#pragma unroll
    for (int r = 0; r < DTR; ++r) s += Ds[ll][r] * wr[r];
    float dv = (s > 20.f) ? s : __logf(1.f + __expf(s));
    float xcv = xc[bl * DIN + d];
    float du = dv * xcv;
    float y = 0.f;
#pragma unroll
    for (int n = 0; n < DST; ++n) {
      float a = __expf(dv * An[n]);
      h[n] = a * h[n] + du * Bs[ll][n];
      y += h[n] * Cs2[ll][n];
    }
    float zv = z[bl * DIN + d];
    float sz = zv / (1.f + __expf(-zv));
    yfin[bl * DIN + d] = (y + xcv * Dd) * sz;
  }
}

// ------- out_proj GEMM: y (16384,256) @ W(128,256)^T -> partials (split-K x2) -------
// M=64 tile, N=128, per-thread 4x8. Grid = 256 m-tiles * 2 k-halves = 512 blocks
// (2 blocks/CU, 8 waves/CU -> fixes the 5%-occupancy 128-block v3).
__global__ __launch_bounds__(256) void k_outproj(const float* __restrict__ Y,
                                                 const float* __restrict__ W,
                                                 float* __restrict__ Pp) {
  const int bid = blockIdx.x;
  const int sk = bid & 1;
  const int bm = (bid >> 1) * 64;
  __shared__ float As[64 * 20];
  __shared__ float Ws[16 * 132];
  const int tid = threadIdx.x;
  const int tx = tid & 15, ty = tid >> 4;
  const int swz = (ty & 3) * 4;
  float acc[4][8] = {};
  const int kbeg = sk * 128, kend = kbeg + 128;
  for (int k0 = kbeg; k0 < kend; k0 += 16) {
    {
      int r = tid >> 2, kq = tid & 3;
      float4 v = *reinterpret_cast<const float4*>(Y + (size_t)(bm + r) * DIN + k0 + kq * 4);
      int kk = (kq * 4) ^ (((r >> 2) & 3) * 4);
      *reinterpret_cast<float4*>(&As[r * 20 + kk]) = v;
    }
    for (int t = 0; t < 2; ++t) {
      int f = tid + t * 256;
      int n = f >> 2, kq = f & 3;
      float4 v = *reinterpret_cast<const float4*>(W + (size_t)n * DIN + k0 + kq * 4);
      Ws[(kq * 4 + 0) * 132 + n] = v.x;
      Ws[(kq * 4 + 1) * 132 + n] = v.y;
      Ws[(kq * 4 + 2) * 132 + n] = v.z;
      Ws[(kq * 4 + 3) * 132 + n] = v.w;
    }
    __syncthreads();
#pragma unroll 4
    for (int k = 0; k < 16; ++k) {
      const int ks = k ^ swz;
      float a[4], b[8];
#pragma unroll
      for (int i = 0; i < 4; ++i) a[i] = As[(ty * 4 + i) * 20 + ks];
      float4 b0 = *reinterpret_cast<const float4*>(&Ws[k * 132 + tx * 8]);
      float4 b1 = *reinterpret_cast<const float4*>(&Ws[k * 132 + tx * 8 + 4]);
      b[0] = b0.x; b[1] = b0.y; b[2] = b0.z; b[3] = b0.w;
      b[4] = b1.x; b[5] = b1.y; b[6] = b1.z; b[7] = b1.w;
#pragma unroll
      for (int i = 0; i < 4; ++i)
#pragma unroll
        for (int j = 0; j < 8; ++j) acc[i][j] += a[i] * b[j];
    }
    __syncthreads();
  }
  float* dst = Pp + (size_t)sk * ((size_t)B_ * L_ * CDIM) + (size_t)bm * CDIM;
  for (int i = 0; i < 4; ++i) {
    size_t row = (size_t)(ty * 4 + i) * CDIM;
    float4 v0 = {acc[i][0], acc[i][1], acc[i][2], acc[i][3]};
    float4 v1 = {acc[i][4], acc[i][5], acc[i][6], acc[i][7]};
    *reinterpret_cast<float4*>(dst + row + tx * 8)     = v0;
    *reinterpret_cast<float4*>(dst + row + tx * 8 + 4) = v1;
  }
}

// ---- out_proj reduce: sum 2 split-K partials, write transposed (B,C,L) ----
__global__ __launch_bounds__(256) void k_oreduce(const float* __restrict__ Pp,
                                                 float* __restrict__ out) {
  const int bm = blockIdx.x * 64;   // 256 blocks
  __shared__ float t[CDIM][65];
  const float* p0 = Pp + (size_t)bm * CDIM;
  const float* p1 = p0 + (size_t)B_ * L_ * CDIM;
  for (int i = threadIdx.x; i < 64 * 32; i += 256) {
    int r = i >> 5, nq = (i & 31) * 4;
    float4 a = *reinterpret_cast<const float4*>(p0 + (size_t)r * CDIM + nq);
    float4 bq = *reinterpret_cast<const float4*>(p1 + (size_t)r * CDIM + nq);
    t[nq + 0][r] = a.x + bq.x;
    t[nq + 1][r] = a.y + bq.y;
    t[nq + 2][r] = a.z + bq.z;
    t[nq + 3][r] = a.w + bq.w;
  }
  __syncthreads();
  const int b = bm >> 12, l0 = bm & (L_ - 1);
  for (int i = threadIdx.x; i < CDIM * 16; i += 256) {
    int n = i >> 4, lq = (i & 15) * 4;
    float4 v = {t[n][lq], t[n][lq + 1], t[n][lq + 2], t[n][lq + 3]};
    *reinterpret_cast<float4*>(out + ((size_t)(b * CDIM + n)) * L_ + l0 + lq) = v;
  }
}

extern "C" void kernel_launch(void* const* d_in, const int* in_sizes, int n_in,
                              void* d_out, int out_size, void* d_ws, size_t ws_size,
                              hipStream_t stream) {
  const float* x        = (const float*)d_in[0];
  const float* norm_w   = (const float*)d_in[1];
  const float* norm_b   = (const float*)d_in[2];
  const float* in_w     = (const float*)d_in[3];
  const float* conv_w   = (const float*)d_in[4];
  const float* conv_b   = (const float*)d_in[5];
  const float* xproj_w  = (const float*)d_in[6];
  const float* dt_w     = (const float*)d_in[7];
  const float* dt_b     = (const float*)d_in[8];
  const float* A_log    = (const float*)d_in[9];
  const float* Dp       = (const float*)d_in[10];
  const float* out_w    = (const float*)d_in[11];
  float* out = (float*)d_out;

  const size_t NBL = (size_t)B_ * L_;           // 16384
  float* ws = (float*)d_ws;
  float* xn    = ws;                            // 2,097,152
  float* xin   = xn + NBL * CDIM;               // 4,194,304 (reused as yfin)
  float* z     = xin + NBL * DIN;               // 4,194,304
  float* xc    = z + NBL * DIN;                 // 4,194,304
  float* ppart = xc + NBL * DIN;                // 4,194,304 (2 x 16384 x 128 split-K partials)
  float* dbl   = ppart + NBL * DIN;             // 655,360
  float* P     = dbl + NBL * 40;                // 1,048,576
  float* Q     = P + (size_t)B_ * NC * DIN * DST;
  float* Hin   = Q + (size_t)B_ * NC * DIN * DST;
  float* yfin  = xin;  // xin is dead after k_conv

  k_ln<<<dim3(L_ / 64, B_), 256, 0, stream>>>(x, norm_w, norm_b, xn);
  k_inproj<<<512, 256, 0, stream>>>(xn, in_w, xin, z);
  k_conv<<<(B_ * L_ * DIN) / 256, 256, 0, stream>>>(xin, conv_w, conv_b, xc);
  k_xproj<<<NBL / 64, 256, 0, stream>>>(xc, xproj_w, dbl);
  k_scan1<<<dim3(NC, B_), 256, 0, stream>>>(xc, dbl, dt_w, dt_b, A_log, P, Q);
  k_scan2<<<(B_ * DIN * DST) / 256, 256, 0, stream>>>(P, Q, Hin);
  k_scan3<<<dim3(NC, B_), 256, 0, stream>>>(xc, dbl, dt_w, dt_b, A_log, Hin, Dp, z, yfin);
  k_outproj<<<512, 256, 0, stream>>>(yfin, out_w, ppart);
  k_oreduce<<<NBL / 64, 256, 0, stream>>>(ppart, out);
}

// Round 5
// 295.706 us; speedup vs baseline: 1.2840x; 1.0640x over previous
//
#include <hip/hip_runtime.h>
#include <hip/hip_bf16.h>

// Mamba 2D layer, fp32. B=4, C=128, H=W=64 -> L=4096.
// D_INNER=256, D_STATE=16, D_CONV=4, DT_RANK=8.
#define B_ 4
#define CDIM 128
#define L_ 4096
#define DIN 256
#define DST 16
#define DTR 8
#define NC 128  // scan chunks (R5: 64->128 for 2x block parallelism)
#define CS 32   // chunk size (L_/NC)

// ---------------- LayerNorm: x (B,C,L) -> xn (B,L,C) ----------------
__global__ __launch_bounds__(256) void k_ln(const float* __restrict__ x,
                                            const float* __restrict__ nw,
                                            const float* __restrict__ nb,
                                            float* __restrict__ xn) {
  const int b = blockIdx.y;
  const int l0 = blockIdx.x * 64;
  __shared__ float xs[64][129];
  __shared__ float mu[64], rs[64];
  for (int i = threadIdx.x; i < CDIM * 64; i += 256) {
    int c = i >> 6, ll = i & 63;           // coalesced over l
    xs[ll][c] = x[((size_t)(b * CDIM + c)) * L_ + l0 + ll];
  }
  __syncthreads();
  if (threadIdx.x < 64) {
    int ll = threadIdx.x;
    float s = 0.f;
    for (int c = 0; c < CDIM; ++c) s += xs[ll][c];
    float m = s * (1.f / CDIM);
    float v = 0.f;
    for (int c = 0; c < CDIM; ++c) { float t = xs[ll][c] - m; v += t * t; }
    mu[ll] = m;
    rs[ll] = rsqrtf(v * (1.f / CDIM) + 1e-5f);
  }
  __syncthreads();
  for (int i = threadIdx.x; i < CDIM * 64; i += 256) {
    int ll = i >> 7, c = i & 127;          // coalesced over c
    float v = (xs[ll][c] - mu[ll]) * rs[ll] * nw[c] + nb[c];
    xn[((size_t)(b * L_ + l0 + ll)) * CDIM + c] = v;
  }
}

// ------------- in_proj: xn (16384,128) @ W(512,128)^T -> xin, z -------------
// 128x128 tile, 8x8 per-thread regs, XCD-swizzled grid (A fetched once/XCD).
__global__ __launch_bounds__(256) void k_inproj(const float* __restrict__ A,
                                                const float* __restrict__ W,
                                                float* __restrict__ xin,
                                                float* __restrict__ z) {
  const int bid = blockIdx.x;        // 512 blocks
  const int xcd = bid & 7, slot = bid >> 3;
  const int bm = (xcd * 16 + (slot >> 2)) * 128;
  const int bn = (slot & 3) * 128;
  __shared__ float As[128 * 20];
  __shared__ float Ws[16 * 132];
  const int tid = threadIdx.x;
  const int tx = tid & 15, ty = tid >> 4;
  const int swz = (ty & 3) * 4;
  float acc[8][8] = {};
  for (int k0 = 0; k0 < CDIM; k0 += 16) {
    for (int t = 0; t < 2; ++t) {
      int f = tid + t * 256;
      int r = f >> 2, kq = f & 3;
      float4 v = *reinterpret_cast<const float4*>(A + (size_t)(bm + r) * CDIM + k0 + kq * 4);
      int kk = (kq * 4) ^ (((r >> 3) & 3) * 4);
      *reinterpret_cast<float4*>(&As[r * 20 + kk]) = v;
    }
    for (int t = 0; t < 2; ++t) {
      int f = tid + t * 256;
      int n = f >> 2, kq = f & 3;
      float4 v = *reinterpret_cast<const float4*>(W + (size_t)(bn + n) * CDIM + k0 + kq * 4);
      Ws[(kq * 4 + 0) * 132 + n] = v.x;
      Ws[(kq * 4 + 1) * 132 + n] = v.y;
      Ws[(kq * 4 + 2) * 132 + n] = v.z;
      Ws[(kq * 4 + 3) * 132 + n] = v.w;
    }
    __syncthreads();
#pragma unroll 4
    for (int k = 0; k < 16; ++k) {
      const int ks = k ^ swz;
      float a[8], b[8];
#pragma unroll
      for (int i = 0; i < 8; ++i) a[i] = As[(ty * 8 + i) * 20 + ks];
      float4 b0 = *reinterpret_cast<const float4*>(&Ws[k * 132 + tx * 8]);
      float4 b1 = *reinterpret_cast<const float4*>(&Ws[k * 132 + tx * 8 + 4]);
      b[0] = b0.x; b[1] = b0.y; b[2] = b0.z; b[3] = b0.w;
      b[4] = b1.x; b[5] = b1.y; b[6] = b1.z; b[7] = b1.w;
#pragma unroll
      for (int i = 0; i < 8; ++i)
#pragma unroll
        for (int j = 0; j < 8; ++j) acc[i][j] += a[i] * b[j];
    }
    __syncthreads();
  }
  float* dst = (bn < DIN) ? xin : z;
  const int nc0 = (bn < DIN) ? bn : bn - DIN;
  for (int i = 0; i < 8; ++i) {
    size_t m = bm + ty * 8 + i;
    float4 v0 = {acc[i][0], acc[i][1], acc[i][2], acc[i][3]};
    float4 v1 = {acc[i][4], acc[i][5], acc[i][6], acc[i][7]};
    *reinterpret_cast<float4*>(dst + m * DIN + nc0 + tx * 8)     = v0;
    *reinterpret_cast<float4*>(dst + m * DIN + nc0 + tx * 8 + 4) = v1;
  }
}

// ---------------- causal conv (d_conv=4) + SiLU ----------------
__global__ void k_conv(const float* __restrict__ xin, const float* __restrict__ cw,
                       const float* __restrict__ cb, float* __restrict__ xc) {
  int idx = blockIdx.x * 256 + threadIdx.x;
  if (idx >= B_ * L_ * DIN) return;
  int d = idx & 255;
  int bl = idx >> 8;
  int l = bl & (L_ - 1);
  int b = bl >> 12;
  float acc = cb[d];
  for (int k = 0; k < 4; ++k) {
    int ls = l + k - 3;
    float v = (ls >= 0) ? xin[((size_t)(b * L_ + ls)) * DIN + d] : 0.f;
    acc += v * cw[d * 4 + k];
  }
  xc[idx] = acc / (1.f + __expf(-acc));  // silu
}

// ---- x_proj: xc (16384,256) @ W(40,256)^T -> dbl, GEMM w/ 64-wide N tile ----
__global__ __launch_bounds__(256) void k_xproj(const float* __restrict__ xc,
                                               const float* __restrict__ w,
                                               float* __restrict__ dbl) {
  const int bm = blockIdx.x * 64;   // row tile
  __shared__ float As[32][65];
  __shared__ float Ws[32][65];
  float acc[4][4] = {};
  const int tx = threadIdx.x & 15, ty = threadIdx.x >> 4;
  for (int k0 = 0; k0 < DIN; k0 += 32) {
    for (int i = threadIdx.x; i < 64 * 32; i += 256) {
      int m = i >> 5, k = i & 31;
      As[k][m] = xc[(size_t)(bm + m) * DIN + k0 + k];
    }
    for (int i = threadIdx.x; i < 64 * 32; i += 256) {
      int n = i >> 5, k = i & 31;
      Ws[k][n] = (n < 40) ? w[(size_t)n * DIN + k0 + k] : 0.f;
    }
    __syncthreads();
    for (int k = 0; k < 32; ++k) {
      float a[4], bv[4];
      for (int i = 0; i < 4; ++i) a[i] = As[k][ty * 4 + i];
      for (int j = 0; j < 4; ++j) bv[j] = Ws[k][tx * 4 + j];
      for (int i = 0; i < 4; ++i)
        for (int j = 0; j < 4; ++j) acc[i][j] += a[i] * bv[j];
    }
    __syncthreads();
  }
  for (int i = 0; i < 4; ++i) {
    int m = bm + ty * 4 + i;
    for (int j = 0; j < 4; ++j) {
      int n = tx * 4 + j;
      if (n < 40) dbl[(size_t)m * 40 + n] = acc[i][j];
    }
  }
}

// -------- scan pass 1 (delta fused, quad n-split): per-chunk (P, Q) --------
// Lane quad (ng=0..3) shares one d and covers 4 states each -> grid gets a
// x4 d-group dim: 128*4*4 = 2048 blocks = 8 blocks/CU = 32 waves/CU (was 1).
__global__ __launch_bounds__(256) void k_scan1(const float* __restrict__ xc,
                                               const float* __restrict__ dbl,
                                               const float* __restrict__ dtw,
                                               const float* __restrict__ dtb,
                                               const float* __restrict__ A_log,
                                               float* __restrict__ P,
                                               float* __restrict__ Q) {
  const int b = blockIdx.y, c = blockIdx.x, dg = blockIdx.z;
  const int tid = threadIdx.x;
  const int dl = tid >> 2, ng = tid & 3;
  const int d = dg * 64 + dl;
  const int l0 = c * CS;
  __shared__ __align__(16) float Bs[CS][DST];
  __shared__ float Ds[CS][DTR];
  for (int i = tid; i < CS * DST; i += 256) {
    int ll = i >> 4, n = i & 15;
    Bs[ll][n] = dbl[((size_t)(b * L_ + l0 + ll)) * 40 + DTR + n];
  }
  for (int i = tid; i < CS * DTR; i += 256) {
    int ll = i >> 3, r = i & 7;
    Ds[ll][r] = dbl[((size_t)(b * L_ + l0 + ll)) * 40 + r];
  }
  float An[4];
  for (int j = 0; j < 4; ++j) An[j] = -__expf(A_log[d * DST + ng * 4 + j]);
  float wr[DTR];
  for (int r = 0; r < DTR; ++r) wr[r] = dtw[d * DTR + r];
  const float bias = dtb[d];
  float p[4] = {1.f, 1.f, 1.f, 1.f}, q[4] = {0.f, 0.f, 0.f, 0.f};
  __syncthreads();
  for (int ll = 0; ll < CS; ++ll) {
    size_t bl = (size_t)(b * L_ + l0 + ll);
    float s = bias;
#pragma unroll
    for (int r = 0; r < DTR; ++r) s += Ds[ll][r] * wr[r];
    float dv = (s > 20.f) ? s : __logf(1.f + __expf(s));
    float du = dv * xc[bl * DIN + d];
    float4 Bv = *reinterpret_cast<const float4*>(&Bs[ll][ng * 4]);
    float Bj[4] = {Bv.x, Bv.y, Bv.z, Bv.w};
#pragma unroll
    for (int j = 0; j < 4; ++j) {
      float a = __expf(dv * An[j]);
      p[j] *= a;
      q[j] = a * q[j] + du * Bj[j];
    }
  }
  size_t base = (((size_t)b * NC + c) * DIN + d) * DST + ng * 4;
  float4 pv = {p[0], p[1], p[2], p[3]};
  float4 qv = {q[0], q[1], q[2], q[3]};
  *reinterpret_cast<float4*>(P + base) = pv;
  *reinterpret_cast<float4*>(Q + base) = qv;
}

// ---------------- scan pass 2: sequential combine over chunks ----------------
__global__ void k_scan2(const float* __restrict__ P, const float* __restrict__ Q,
                        float* __restrict__ Hin) {
  int idx = blockIdx.x * 256 + threadIdx.x;  // B*DIN*DST = 16384
  int b = idx / (DIN * DST);
  int dn = idx % (DIN * DST);
  float h = 0.f;
  size_t base = ((size_t)b * NC) * (DIN * DST) + dn;
  float p = P[base], q = Q[base];
  for (int c = 0; c < NC; ++c) {
    size_t nb = base + (size_t)(c + 1) * (DIN * DST);
    float pn = 0.f, qn = 0.f;
    if (c + 1 < NC) { pn = P[nb]; qn = Q[nb]; }
    Hin[base + (size_t)c * (DIN * DST)] = h;
    h = p * h + q;
    p = pn; q = qn;
  }
}

// -- scan pass 3 (delta fused, quad n-split): replay w/ entry state, D/z-gate --
// y reduced across the lane quad with two shfl_xor (no barrier).
__global__ __launch_bounds__(256) void k_scan3(const float* __restrict__ xc,
                                               const float* __restrict__ dbl,
                                               const float* __restrict__ dtw,
                                               const float* __restrict__ dtb,
                                               const float* __restrict__ A_log,
                                               const float* __restrict__ Hin,
                                               const float* __restrict__ Dp,
                                               const float* __restrict__ z,
                                               float* __restrict__ yfin) {
  const int b = blockIdx.y, c = blockIdx.x, dg = blockIdx.z;
  const int tid = threadIdx.x;
  const int dl = tid >> 2, ng = tid & 3;
  const int d = dg * 64 + dl;
  const int l0 = c * CS;
  __shared__ __align__(16) float Bs[CS][DST];
  __shared__ __align__(16) float Cs2[CS][DST];
  __shared__ float Ds[CS][DTR];
  for (int i = tid; i < CS * DST; i += 256) {
    int ll = i >> 4, n = i & 15;
    size_t base = ((size_t)(b * L_ + l0 + ll)) * 40;
    Bs[ll][n]  = dbl[base + DTR + n];
    Cs2[ll][n] = dbl[base + DTR + DST + n];
  }
  for (int i = tid; i < CS * DTR; i += 256) {
    int ll = i >> 3, r = i & 7;
    Ds[ll][r] = dbl[((size_t)(b * L_ + l0 + ll)) * 40 + r];
  }
  float An[4];
  for (int j = 0; j < 4; ++j) An[j] = -__expf(A_log[d * DST + ng * 4 + j]);
  float wr[DTR];
  for (int r = 0; r < DTR; ++r) wr[r] = dtw[d * DTR + r];
  const float bias = dtb[d];
  size_t hb = (((size_t)b * NC + c) * DIN + d) * DST + ng * 4;
  float4 hv = *reinterpret_cast<const float4*>(Hin + hb);
  float h[4] = {hv.x, hv.y, hv.z, hv.w};
  const float Dd = Dp[d];
  __syncthreads();
  for (int ll = 0; ll < CS; ++ll) {
    size_t bl = (size_t)(b * L_ + l0 + ll);
    float s = bias;
#pragma unroll
    for (int r = 0; r < DTR; ++r) s += Ds[ll][r] * wr[r];
    float dv = (s > 20.f) ? s : __logf(1.f + __expf(s));
    float xcv = xc[bl * DIN + d];
    float du = dv * xcv;
    float4 Bv = *reinterpret_cast<const float4*>(&Bs[ll][ng * 4]);
    float4 Cv = *reinterpret_cast<const float4*>(&Cs2[ll][ng * 4]);
    float Bj[4] = {Bv.x, Bv.y, Bv.z, Bv.w};
    float Cj[4] = {Cv.x, Cv.y, Cv.z, Cv.w};
    float y = 0.f;
#pragma unroll
    for (int j = 0; j < 4; ++j) {
      float a = __expf(dv * An[j]);
      h[j] = a * h[j] + du * Bj[j];
      y += h[j] * Cj[j];
    }
    y += __shfl_xor(y, 1);
    y += __shfl_xor(y, 2);
    if (ng == 0) {
      float zv = z[bl * DIN + d];
      float sz = zv / (1.f + __expf(-zv));
      yfin[bl * DIN + d] = (y + xcv * Dd) * sz;
    }
  }
}

// ------- out_proj GEMM: y (16384,256) @ W(128,256)^T -> partials (split-K x2) -------
// M=64 tile, N=128, per-thread 4x8. Grid = 256 m-tiles * 2 k-halves = 512 blocks.
__global__ __launch_bounds__(256) void k_outproj(const float* __restrict__ Y,
                                                 const float* __restrict__ W,
                                                 float* __restrict__ Pp) {
  const int bid = blockIdx.x;
  const int sk = bid & 1;
  const int bm = (bid >> 1) * 64;
  __shared__ float As[64 * 20];
  __shared__ float Ws[16 * 132];
  const int tid = threadIdx.x;
  const int tx = tid & 15, ty = tid >> 4;
  const int swz = (ty & 3) * 4;
  float acc[4][8] = {};
  const int kbeg = sk * 128, kend = kbeg + 128;
  for (int k0 = kbeg; k0 < kend; k0 += 16) {
    {
      int r = tid >> 2, kq = tid & 3;
      float4 v = *reinterpret_cast<const float4*>(Y + (size_t)(bm + r) * DIN + k0 + kq * 4);
      int kk = (kq * 4) ^ (((r >> 2) & 3) * 4);
      *reinterpret_cast<float4*>(&As[r * 20 + kk]) = v;
    }
    for (int t = 0; t < 2; ++t) {
      int f = tid + t * 256;
      int n = f >> 2, kq = f & 3;
      float4 v = *reinterpret_cast<const float4*>(W + (size_t)n * DIN + k0 + kq * 4);
      Ws[(kq * 4 + 0) * 132 + n] = v.x;
      Ws[(kq * 4 + 1) * 132 + n] = v.y;
      Ws[(kq * 4 + 2) * 132 + n] = v.z;
      Ws[(kq * 4 + 3) * 132 + n] = v.w;
    }
    __syncthreads();
#pragma unroll 4
    for (int k = 0; k < 16; ++k) {
      const int ks = k ^ swz;
      float a[4], b[8];
#pragma unroll
      for (int i = 0; i < 4; ++i) a[i] = As[(ty * 4 + i) * 20 + ks];
      float4 b0 = *reinterpret_cast<const float4*>(&Ws[k * 132 + tx * 8]);
      float4 b1 = *reinterpret_cast<const float4*>(&Ws[k * 132 + tx * 8 + 4]);
      b[0] = b0.x; b[1] = b0.y; b[2] = b0.z; b[3] = b0.w;
      b[4] = b1.x; b[5] = b1.y; b[6] = b1.z; b[7] = b1.w;
#pragma unroll
      for (int i = 0; i < 4; ++i)
#pragma unroll
        for (int j = 0; j < 8; ++j) acc[i][j] += a[i] * b[j];
    }
    __syncthreads();
  }
  float* dst = Pp + (size_t)sk * ((size_t)B_ * L_ * CDIM) + (size_t)bm * CDIM;
  for (int i = 0; i < 4; ++i) {
    size_t row = (size_t)(ty * 4 + i) * CDIM;
    float4 v0 = {acc[i][0], acc[i][1], acc[i][2], acc[i][3]};
    float4 v1 = {acc[i][4], acc[i][5], acc[i][6], acc[i][7]};
    *reinterpret_cast<float4*>(dst + row + tx * 8)     = v0;
    *reinterpret_cast<float4*>(dst + row + tx * 8 + 4) = v1;
  }
}

// ---- out_proj reduce: sum 2 split-K partials, write transposed (B,C,L) ----
__global__ __launch_bounds__(256) void k_oreduce(const float* __restrict__ Pp,
                                                 float* __restrict__ out) {
  const int bm = blockIdx.x * 64;   // 256 blocks
  __shared__ float t[CDIM][65];
  const float* p0 = Pp + (size_t)bm * CDIM;
  const float* p1 = p0 + (size_t)B_ * L_ * CDIM;
  for (int i = threadIdx.x; i < 64 * 32; i += 256) {
    int r = i >> 5, nq = (i & 31) * 4;
    float4 a = *reinterpret_cast<const float4*>(p0 + (size_t)r * CDIM + nq);
    float4 bq = *reinterpret_cast<const float4*>(p1 + (size_t)r * CDIM + nq);
    t[nq + 0][r] = a.x + bq.x;
    t[nq + 1][r] = a.y + bq.y;
    t[nq + 2][r] = a.z + bq.z;
    t[nq + 3][r] = a.w + bq.w;
  }
  __syncthreads();
  const int b = bm >> 12, l0 = bm & (L_ - 1);
  for (int i = threadIdx.x; i < CDIM * 16; i += 256) {
    int n = i >> 4, lq = (i & 15) * 4;
    float4 v = {t[n][lq], t[n][lq + 1], t[n][lq + 2], t[n][lq + 3]};
    *reinterpret_cast<float4*>(out + ((size_t)(b * CDIM + n)) * L_ + l0 + lq) = v;
  }
}

extern "C" void kernel_launch(void* const* d_in, const int* in_sizes, int n_in,
                              void* d_out, int out_size, void* d_ws, size_t ws_size,
                              hipStream_t stream) {
  const float* x        = (const float*)d_in[0];
  const float* norm_w   = (const float*)d_in[1];
  const float* norm_b   = (const float*)d_in[2];
  const float* in_w     = (const float*)d_in[3];
  const float* conv_w   = (const float*)d_in[4];
  const float* conv_b   = (const float*)d_in[5];
  const float* xproj_w  = (const float*)d_in[6];
  const float* dt_w     = (const float*)d_in[7];
  const float* dt_b     = (const float*)d_in[8];
  const float* A_log    = (const float*)d_in[9];
  const float* Dp       = (const float*)d_in[10];
  const float* out_w    = (const float*)d_in[11];
  float* out = (float*)d_out;

  const size_t NBL = (size_t)B_ * L_;           // 16384
  float* ws = (float*)d_ws;
  float* xn    = ws;                            // 2,097,152
  float* xin   = xn + NBL * CDIM;               // 4,194,304 (reused as yfin)
  float* z     = xin + NBL * DIN;               // 4,194,304
  float* xc    = z + NBL * DIN;                 // 4,194,304
  float* ppart = xc + NBL * DIN;                // 4,194,304 (2 x 16384 x 128 split-K partials)
  float* dbl   = ppart + NBL * DIN;             // 655,360
  float* P     = dbl + NBL * 40;                // 2,097,152 (NC=128)
  float* Q     = P + (size_t)B_ * NC * DIN * DST;
  float* Hin   = Q + (size_t)B_ * NC * DIN * DST;
  float* yfin  = xin;  // xin is dead after k_conv

  k_ln<<<dim3(L_ / 64, B_), 256, 0, stream>>>(x, norm_w, norm_b, xn);
  k_inproj<<<512, 256, 0, stream>>>(xn, in_w, xin, z);
  k_conv<<<(B_ * L_ * DIN) / 256, 256, 0, stream>>>(xin, conv_w, conv_b, xc);
  k_xproj<<<NBL / 64, 256, 0, stream>>>(xc, xproj_w, dbl);
  k_scan1<<<dim3(NC, B_, 4), 256, 0, stream>>>(xc, dbl, dt_w, dt_b, A_log, P, Q);
  k_scan2<<<(B_ * DIN * DST) / 256, 256, 0, stream>>>(P, Q, Hin);
  k_scan3<<<dim3(NC, B_, 4), 256, 0, stream>>>(xc, dbl, dt_w, dt_b, A_log, Hin, Dp, z, yfin);
  k_outproj<<<512, 256, 0, stream>>>(yfin, out_w, ppart);
  k_oreduce<<<NBL / 64, 256, 0, stream>>>(ppart, out);
}